// Round 5
// baseline (447.457 us; speedup 1.0000x reference)
//
#include <hip/hip_runtime.h>
#include <hip/hip_cooperative_groups.h>

namespace cg = cooperative_groups;

typedef unsigned short ushort_t;
typedef __attribute__((ext_vector_type(8))) short short8;   // 8 x bf16 (MFMA A/B frag)
typedef __attribute__((ext_vector_type(4))) float floatx4;  // MFMA C/D frag

// Problem constants: N=4000, E=60000, M=16, C=64, H=64, HEADS=8, A=8, VC=8, CE=32, Z=90
// cmp (fp32, per role stride RS): WeWa [32*64] @8192, WeWvWo [32*8] @11264 (rest unused)
// packW (ushort, 18432): W frags [mat 0..3][ (t*2+kh) 0..7 ][lane 0..63][j 0..7]  (mat: r0S,r0T,r1S,r1T)
//                        + P frags @16384: [mat Ps/Pt][kh 0..1][lane 0..63][j 0..7]
constexpr int RS = 11520;

__device__ inline float bf2f(ushort_t u) {
    union { unsigned int i; float f; } v; v.i = ((unsigned int)u) << 16; return v.f;
}
__device__ inline ushort_t f2bf(float f) {
    union { float f; unsigned int i; } v; v.f = f;
    unsigned int b = v.i + 0x7FFFu + ((v.i >> 16) & 1u);  // RNE
    return (ushort_t)(b >> 16);
}
__device__ inline void st4(ushort_t* dst, const floatx4& c) {
    uint2 v;
    v.x = (unsigned int)f2bf(c[0]) | ((unsigned int)f2bf(c[1]) << 16);
    v.y = (unsigned int)f2bf(c[2]) | ((unsigned int)f2bf(c[3]) << 16);
    *(uint2*)dst = v;
}

#define MFMA(a, b, c) __builtin_amdgcn_mfma_f32_16x16x32_bf16((a), (b), (c), 0, 0, 0)

// ---------------------------------------------------------------------------
// Kernel PRE (cooperative, 256 blocks x 256 thr):
//   phase 0: zero bins        (all blocks)
//   phase 1: histogram of dst (all blocks)
//   phase 2: weight composites (blocks 0..47)  ||  exclusive scan (block 48)
//   phase 3: scatter -> order[] = edges sorted by dst (counting sort)
// No early returns anywhere (grid.sync discipline).
// ---------------------------------------------------------------------------
__global__ __launch_bounds__(256) void k_pre(
    const float* __restrict__ Ws0, const float* __restrict__ Wt0, const float* __restrict__ We0,
    const float* __restrict__ Wa0, const float* __restrict__ Wv0, const float* __restrict__ Wo0,
    const float* __restrict__ Ws1, const float* __restrict__ Wt1, const float* __restrict__ We1,
    const float* __restrict__ Wa1, const float* __restrict__ Wv1, const float* __restrict__ Wo1,
    const int* __restrict__ ei, float* __restrict__ cmp, ushort_t* __restrict__ packW,
    int* __restrict__ binCnt, int* __restrict__ binPos, int* __restrict__ order,
    int N, int E)
{
    cg::grid_group g = cg::this_grid();
    __shared__ int part[256];
    int tid = blockIdx.x * 256 + threadIdx.x;
    int nT  = gridDim.x * 256;

    // phase 0: zero bins
    for (int i = tid; i < N; i += nT) binCnt[i] = 0;
    g.sync();
    // phase 1: histogram over dst
    for (int e = tid; e < E; e += nT) atomicAdd(&binCnt[ei[E + e]], 1);
    g.sync();

    // phase 2a: composites on blocks 0..47
    int b = blockIdx.x;
    if (b < 48) {
        int task = b % 6, r = (b / 6) % 2, z = b / 12;
        const float* Ws = r ? Ws1 : Ws0;
        const float* Wt = r ? Wt1 : Wt0;
        const float* We = r ? We1 : We0;
        const float* Wa = r ? Wa1 : Wa0;
        const float* Wv = r ? Wv1 : Wv0;
        const float* Wo = r ? Wo1 : Wo0;
        float* base = cmp + r * RS;

        if (task == 0 || task == 1) {
            // WsWa / WtWa -> fragment-packed bf16 only
            const float* L = task ? Wt : Ws;
            ushort_t* pw = packW + (r * 2 + task) * 4096;
            int lo = z * 1024;
            for (int idx = lo + threadIdx.x; idx < lo + 1024; idx += 256) {
                int c = idx >> 6, jc = idx & 63;
                float a = 0.f;
                #pragma unroll 8
                for (int k = 0; k < 64; ++k) a += L[c * 64 + k] * Wa[k * 64 + jc];
                int t = jc >> 4, n = jc & 15, kh = c >> 5, q = (c >> 3) & 3, jj = c & 7;
                pw[((t * 2 + kh) * 64 + q * 16 + n) * 8 + jj] = f2bf(a);
            }
        } else if (task == 2) {
            float* out = base + 8192;                       // WeWa linear fp32
            int lo = z * 512;
            for (int idx = lo + threadIdx.x; idx < lo + 512; idx += 256) {
                int ce = idx >> 6, jc = idx & 63;
                float a = 0.f;
                #pragma unroll 8
                for (int k = 0; k < 64; ++k) a += We[ce * 64 + k] * Wa[k * 64 + jc];
                out[idx] = a;
            }
        } else if (z == 0) {
            if (task == 5) {
                float* out = base + 11264;                  // WeWvWo linear fp32
                for (int idx = threadIdx.x; idx < 32 * 8; idx += 256) {
                    int c = idx >> 3, h = idx & 7;
                    float a = 0.f;
                    for (int k = 0; k < 64; ++k) {
                        float wv = 0.f;
                        #pragma unroll
                        for (int aa = 0; aa < 8; ++aa) wv += Wv[k * 64 + h * 8 + aa] * Wo[h * 8 + aa];
                        a += We[c * 64 + k] * wv;
                    }
                    out[idx] = a;
                }
            } else {
                // task 3 (Ps) / 4 (Pt): write packed B-frags directly.
                // frag elem: lane(q, n16=r*8+h), kh, j -> P_r[kh*32+q*8+j][h]
                const float* L = (task == 3) ? Ws : Wt;
                ushort_t* pp = packW + 16384 + (task - 3) * 1024;
                for (int idx = threadIdx.x; idx < 64 * 8; idx += 256) {
                    int c = idx >> 3, h = idx & 7;
                    float a = 0.f;
                    for (int k = 0; k < 64; ++k) {
                        float wv = 0.f;
                        #pragma unroll
                        for (int aa = 0; aa < 8; ++aa) wv += Wv[k * 64 + h * 8 + aa] * Wo[h * 8 + aa];
                        a += L[c * 64 + k] * wv;
                    }
                    int kh = c >> 5, q = (c >> 3) & 3, jj = c & 7;
                    pp[kh * 512 + (q * 16 + r * 8 + h) * 8 + jj] = f2bf(a);
                }
            }
        }
    } else if (b == 48) {
        // phase 2b: exclusive scan of binCnt -> binPos (256 threads, chunked)
        int t = threadIdx.x;
        int chunk = (N + 255) / 256;
        int lo = t * chunk, hi = lo + chunk; if (hi > N) hi = N; if (lo > N) lo = N;
        int s = 0;
        for (int i = lo; i < hi; ++i) s += binCnt[i];
        part[t] = s;
        __syncthreads();
        for (int off = 1; off < 256; off <<= 1) {
            int v = (t >= off) ? part[t - off] : 0;
            __syncthreads();
            part[t] += v;
            __syncthreads();
        }
        int start = (t == 0) ? 0 : part[t - 1];
        for (int i = lo; i < hi; ++i) { int c = binCnt[i]; binPos[i] = start; start += c; }
    }
    g.sync();

    // phase 3: scatter (counting sort by dst)
    for (int e = tid; e < E; e += nT) {
        int pos = atomicAdd(&binPos[ei[E + e]], 1);
        order[pos] = e;
    }
}

// ---------------------------------------------------------------------------
// Kernel B: per-node precompute via MFMA. One wave per node, exact grid.
// Weight fragments staged in LDS (36 KB) once per block -> VGPR ~100 instead
// of ~190 (R4 kept 32 frags in registers => 2 waves/SIMD).
// srcA/tgtA stored TRANSPOSED [64 cols][16 rows] bf16 per (node,role).
// Also zeroes den/num (no memset dispatch).
// ---------------------------------------------------------------------------
__global__ __launch_bounds__(256, 4) void k_node(
    const float* __restrict__ x, const int* __restrict__ mask,
    const ushort_t* __restrict__ packW,
    float* __restrict__ psrc, float* __restrict__ ptgt,
    ushort_t* __restrict__ srcA, ushort_t* __restrict__ tgtA,
    float* __restrict__ den, float* __restrict__ num, int N)
{
    __shared__ __align__(16) ushort_t lw[18432];   // 36 KB
    for (int i = threadIdx.x; i < 2304; i += 256)
        ((short8*)lw)[i] = ((const short8*)packW)[i];
    __syncthreads();

    int wid  = (int)((blockIdx.x * blockDim.x + threadIdx.x) >> 6);
    int lane = threadIdx.x & 63;
    int q    = lane >> 4;     // quad 0..3
    int n16  = lane & 15;     // 0..15

    if (wid < N) {
        int nd = wid;
        if (lane < 8)  den[nd * 8 + lane] = 0.f;
        if (lane < 24) num[nd * 24 + lane] = 0.f;

        // A fragments: x[nd] is [16,64] fp32, row m=n16, k base q*8
        const float* xp = x + (size_t)nd * 1024 + n16 * 64 + q * 8;
        float4 v0 = *(const float4*)(xp);
        float4 v1 = *(const float4*)(xp + 4);
        float4 v2 = *(const float4*)(xp + 32);
        float4 v3 = *(const float4*)(xp + 36);
        short8 a0, a1;
        a0[0] = (short)f2bf(v0.x); a0[1] = (short)f2bf(v0.y);
        a0[2] = (short)f2bf(v0.z); a0[3] = (short)f2bf(v0.w);
        a0[4] = (short)f2bf(v1.x); a0[5] = (short)f2bf(v1.y);
        a0[6] = (short)f2bf(v1.z); a0[7] = (short)f2bf(v1.w);
        a1[0] = (short)f2bf(v2.x); a1[1] = (short)f2bf(v2.y);
        a1[2] = (short)f2bf(v2.z); a1[3] = (short)f2bf(v2.w);
        a1[4] = (short)f2bf(v3.x); a1[5] = (short)f2bf(v3.y);
        a1[6] = (short)f2bf(v3.z); a1[7] = (short)f2bf(v3.w);

        int rsel = (mask[nd] != 0);
        const floatx4 zero = {0.f, 0.f, 0.f, 0.f};

        #define WF(mat, t, kh) (*(const short8*)&lw[(mat) * 4096 + ((t) * 2 + (kh)) * 512 + lane * 8])
        #define PF(m, kh)      (*(const short8*)&lw[16384 + (m) * 1024 + (kh) * 512 + lane * 8])

        // srcA role0 (mat 0)
        {
            floatx4 c0 = zero, c1 = zero, c2 = zero, c3 = zero;
            c0 = MFMA(a0, WF(0,0,0), c0); c0 = MFMA(a1, WF(0,0,1), c0);
            c1 = MFMA(a0, WF(0,1,0), c1); c1 = MFMA(a1, WF(0,1,1), c1);
            c2 = MFMA(a0, WF(0,2,0), c2); c2 = MFMA(a1, WF(0,2,1), c2);
            c3 = MFMA(a0, WF(0,3,0), c3); c3 = MFMA(a1, WF(0,3,1), c3);
            ushort_t* sp = srcA + (size_t)nd * 2048 + n16 * 16 + q * 4;
            st4(sp, c0); st4(sp + 256, c1); st4(sp + 512, c2); st4(sp + 768, c3);
        }
        // srcA role1 (mat 2)
        {
            floatx4 c0 = zero, c1 = zero, c2 = zero, c3 = zero;
            c0 = MFMA(a0, WF(2,0,0), c0); c0 = MFMA(a1, WF(2,0,1), c0);
            c1 = MFMA(a0, WF(2,1,0), c1); c1 = MFMA(a1, WF(2,1,1), c1);
            c2 = MFMA(a0, WF(2,2,0), c2); c2 = MFMA(a1, WF(2,2,1), c2);
            c3 = MFMA(a0, WF(2,3,0), c3); c3 = MFMA(a1, WF(2,3,1), c3);
            ushort_t* sp = srcA + (size_t)nd * 2048 + 1024 + n16 * 16 + q * 4;
            st4(sp, c0); st4(sp + 256, c1); st4(sp + 512, c2); st4(sp + 768, c3);
        }
        // tgtA selected role (mat 1 or 3) — wave-uniform branch
        {
            int mt = rsel ? 3 : 1;
            floatx4 c0 = zero, c1 = zero, c2 = zero, c3 = zero;
            c0 = MFMA(a0, WF(mt,0,0), c0); c0 = MFMA(a1, WF(mt,0,1), c0);
            c1 = MFMA(a0, WF(mt,1,0), c1); c1 = MFMA(a1, WF(mt,1,1), c1);
            c2 = MFMA(a0, WF(mt,2,0), c2); c2 = MFMA(a1, WF(mt,2,1), c2);
            c3 = MFMA(a0, WF(mt,3,0), c3); c3 = MFMA(a1, WF(mt,3,1), c3);
            ushort_t* tp = tgtA + (size_t)nd * 1024 + n16 * 16 + q * 4;
            st4(tp, c0); st4(tp + 256, c1); st4(tp + 512, c2); st4(tp + 768, c3);
        }
        // Ps (both roles packed in cols) and Pt (selected role)
        {
            floatx4 cp = zero;
            cp = MFMA(a0, PF(0,0), cp); cp = MFMA(a1, PF(0,1), cp);
            if (q == 0) {  // rows 1..3 live in regs 1..3 of quad 0
                int r = n16 >> 3, h = n16 & 7;
                float* pp = psrc + (size_t)nd * 48 + r * 24 + h;
                pp[0]  = cp[1];
                pp[8]  = cp[2];
                pp[16] = cp[3];
            }
            floatx4 cq = zero;
            cq = MFMA(a0, PF(1,0), cq); cq = MFMA(a1, PF(1,1), cq);
            if (q == 0 && (n16 >> 3) == rsel) {
                int h = n16 & 7;
                float* pp = ptgt + (size_t)nd * 24 + h;
                pp[0]  = cq[1];
                pp[8]  = cq[2];
                pp[16] = cq[3];
            }
        }
        #undef WF
        #undef PF
    }
}

// ---------------------------------------------------------------------------
// Kernel C (fused): per-edge logits + exp + den/num scatter. ONE edge per
// wave, edges visited in dst-sorted order (via order[]) so consecutive waves
// share tgtA/ptgt/mask/zn and den/num lines -> gather re-fetch drops.
//   out[dst,k] = sum_h ( sum_e ex_e * s_e[k,h] ) / den[dst,h]
// ---------------------------------------------------------------------------
__global__ __launch_bounds__(256, 8) void k_fused(
    const int* __restrict__ ei, const float* __restrict__ dist,
    const int* __restrict__ zn, const int* __restrict__ mask,
    const float* __restrict__ wig, const float* __restrict__ cmp,
    const float* __restrict__ embs0, const float* __restrict__ embt0, const float* __restrict__ wd0,
    const float* __restrict__ embs1, const float* __restrict__ embt1, const float* __restrict__ wd1,
    const float* __restrict__ va0, const float* __restrict__ va1,
    const ushort_t* __restrict__ srcA, const ushort_t* __restrict__ tgtA,
    const float* __restrict__ psrc, const float* __restrict__ ptgt,
    const int* __restrict__ order,
    float* __restrict__ den, float* __restrict__ num, int E)
{
    int wv = threadIdx.x >> 6, j = threadIdx.x & 63;
    int el = blockIdx.x * 4 + wv;
    if (el >= E) return;
    int e = order[el];
    int src = ei[e], dst = ei[E + e];
    int r = (mask[dst] != 0);
    float d = dist[e];
    int zs = zn[src], zt = zn[dst];
    int hq = j >> 3, h8 = j & 7;

    // issue all gathers up front (overlap latency with the ce loop)
    const float* w0 = wig + (size_t)e * 256;            // D[0, :]
    float4 wA = *(const float4*)(w0);
    float4 wB = *(const float4*)(w0 + 4);
    float4 wC = *(const float4*)(w0 + 8);
    float4 wD = *(const float4*)(w0 + 12);
    const ushort_t* sa = srcA + (size_t)src * 2048 + r * 1024 + j * 16;
    const ushort_t* ta = tgtA + (size_t)dst * 1024 + j * 16;
    short8 sv0 = *(const short8*)(sa);       // rows 0..7 of col j
    short8 sv1 = *(const short8*)(sa + 8);   // rows 8..15
    short8 tv0 = *(const short8*)(ta);
    short8 tv1 = *(const short8*)(ta + 8);
    float pv = 0.f;
    if (h8 < 3)
        pv = psrc[(size_t)src * 48 + r * 24 + h8 * 8 + hq]
           + ptgt[(size_t)dst * 24 + h8 * 8 + hq];

    // edge scalar embedding (32 values via j&31)
    float es;
    {
        int ce = j & 31;
        float z = r ? (d * wd1[ce] + embs1[zs * 32 + ce] + embt1[zt * 32 + ce])
                    : (d * wd0[ce] + embs0[zs * 32 + ce] + embt0[zt * 32 + ce]);
        es = z / (1.f + __expf(-z));   // silu
    }

    const float* WeWa   = cmp + r * RS + 8192;
    const float* WeWvWo = cmp + r * RS + 11264;
    float f0a = 0.f, ej = 0.f;
    #pragma unroll
    for (int ce = 0; ce < 32; ++ce) {
        float ev = __shfl(es, ce, 64);
        f0a += ev * WeWa[ce * 64 + j];
        ej  += ev * WeWvWo[ce * 8 + hq];
    }

    // f0a[j] += sum_n D[0,n] * (ysa[src][n,j] + yta[dst][n,j]) : in-lane
    f0a += wA.x * (bf2f((ushort_t)sv0[0]) + bf2f((ushort_t)tv0[0]));
    f0a += wA.y * (bf2f((ushort_t)sv0[1]) + bf2f((ushort_t)tv0[1]));
    f0a += wA.z * (bf2f((ushort_t)sv0[2]) + bf2f((ushort_t)tv0[2]));
    f0a += wA.w * (bf2f((ushort_t)sv0[3]) + bf2f((ushort_t)tv0[3]));
    f0a += wB.x * (bf2f((ushort_t)sv0[4]) + bf2f((ushort_t)tv0[4]));
    f0a += wB.y * (bf2f((ushort_t)sv0[5]) + bf2f((ushort_t)tv0[5]));
    f0a += wB.z * (bf2f((ushort_t)sv0[6]) + bf2f((ushort_t)tv0[6]));
    f0a += wB.w * (bf2f((ushort_t)sv0[7]) + bf2f((ushort_t)tv0[7]));
    f0a += wC.x * (bf2f((ushort_t)sv1[0]) + bf2f((ushort_t)tv1[0]));
    f0a += wC.y * (bf2f((ushort_t)sv1[1]) + bf2f((ushort_t)tv1[1]));
    f0a += wC.z * (bf2f((ushort_t)sv1[2]) + bf2f((ushort_t)tv1[2]));
    f0a += wC.w * (bf2f((ushort_t)sv1[3]) + bf2f((ushort_t)tv1[3]));
    f0a += wD.x * (bf2f((ushort_t)sv1[4]) + bf2f((ushort_t)tv1[4]));
    f0a += wD.y * (bf2f((ushort_t)sv1[5]) + bf2f((ushort_t)tv1[5]));
    f0a += wD.z * (bf2f((ushort_t)sv1[6]) + bf2f((ushort_t)tv1[6]));
    f0a += wD.w * (bf2f((ushort_t)sv1[7]) + bf2f((ushort_t)tv1[7]));

    float la = f0a > 0.f ? f0a : 0.2f * f0a;           // leaky_relu(0.2)
    float val = la * (r ? va1[j] : va0[j]);
    val += __shfl_xor(val, 1);
    val += __shfl_xor(val, 2);
    val += __shfl_xor(val, 4);                          // logit per 8-lane group
    float ex = __expf(val);                             // no-max softmax (logits bounded)

    if (h8 == 0) atomicAdd(&den[dst * 8 + hq], ex);
    if (h8 < 3) {
        float w0k = (h8 == 0) ? wA.y : (h8 == 1) ? wA.z : wA.w;  // D[0,1..3]
        atomicAdd(&num[dst * 24 + hq * 3 + h8], ex * (pv + ej * w0k));
    }
}

// ---------------------------------------------------------------------------
// Kernel D: out[n,k] = sum_h num[n,h,k]/(den[n,h]+eps). Writes every element.
// ---------------------------------------------------------------------------
__global__ __launch_bounds__(256) void k_out(
    const float* __restrict__ num, const float* __restrict__ den,
    float* __restrict__ out, int N3)
{
    int t = blockIdx.x * 256 + threadIdx.x;
    if (t >= N3) return;
    int n = t / 3, k = t - n * 3;
    float acc = 0.f;
    #pragma unroll
    for (int h = 0; h < 8; ++h)
        acc += num[n * 24 + h * 3 + k] / (den[n * 8 + h] + 1e-9f);
    out[t] = acc;
}

// ---------------------------------------------------------------------------
extern "C" void kernel_launch(void* const* d_in, const int* in_sizes, int n_in,
                              void* d_out, int out_size, void* d_ws, size_t ws_size,
                              hipStream_t stream) {
    const float* x    = (const float*)d_in[0];
    const int*   zn   = (const int*)d_in[1];
    const float* dist = (const float*)d_in[2];
    const int*   ei   = (const int*)d_in[3];
    const int*   mask = (const int*)d_in[4];
    const float* wig  = (const float*)d_in[5];
    // per role: emb_s, emb_t, w_d, We, Ws, Wt, Wa, va, Wv, Wo
    const float* fs[10]; const float* dn[10];
    for (int i = 0; i < 10; ++i) { fs[i] = (const float*)d_in[6 + i]; dn[i] = (const float*)d_in[16 + i]; }

    int N = in_sizes[1];   // atomic_numbers count
    int E = in_sizes[2];   // edge_distance count

    // workspace carve-up
    float* cmp  = (float*)d_ws;                    // 2*RS = 23040 floats
    float* den  = cmp + 2 * RS;                    // N*8
    float* num  = den + (size_t)N * 8;             // N*24
    float* psrc = num + (size_t)N * 24;            // N*48
    float* ptgt = psrc + (size_t)N * 48;           // N*24
    ushort_t* srcA = (ushort_t*)(ptgt + (size_t)N * 24);  // N*2048 bf16
    ushort_t* tgtA = srcA + (size_t)N * 2048;             // N*1024 bf16
    ushort_t* packW = tgtA + (size_t)N * 1024;            // 18432 ushorts (36 KB)
    int* binCnt = (int*)(packW + 18432);                  // N
    int* binPos = binCnt + N;                             // N
    int* order  = binPos + N;                             // E
    // total ~26.6 MB

    // cooperative pre-pass: composites + counting sort by dst (one dispatch)
    const float *Ws0 = fs[4], *Wt0 = fs[5], *We0 = fs[3], *Wa0 = fs[6], *Wv0 = fs[8], *Wo0 = fs[9];
    const float *Ws1 = dn[4], *Wt1 = dn[5], *We1 = dn[3], *Wa1 = dn[6], *Wv1 = dn[8], *Wo1 = dn[9];
    int Nv = N, Ev = E;
    void* args[] = { &Ws0, &Wt0, &We0, &Wa0, &Wv0, &Wo0,
                     &Ws1, &Wt1, &We1, &Wa1, &Wv1, &Wo1,
                     &ei, &cmp, &packW, &binCnt, &binPos, &order, &Nv, &Ev };
    hipLaunchCooperativeKernel((const void*)k_pre, dim3(256), dim3(256), args, 0, stream);

    int nodeBlocks = (N + 3) / 4;                // one wave per node, exact grid
    k_node<<<nodeBlocks, 256, 0, stream>>>(x, mask, packW, psrc, ptgt,
                                           srcA, tgtA, den, num, N);

    k_fused<<<(E + 3) / 4, 256, 0, stream>>>(
        ei, dist, zn, mask, wig, cmp,
        fs[0], fs[1], fs[2], dn[0], dn[1], dn[2],
        fs[7], dn[7], srcA, tgtA, psrc, ptgt, order, den, num, E);

    k_out<<<(N * 3 + 255) / 256, 256, 0, stream>>>(num, den, (float*)d_out, N * 3);
}

// Round 6
// 264.045 us; speedup vs baseline: 1.6946x; 1.6946x over previous
//
#include <hip/hip_runtime.h>

typedef unsigned short ushort_t;
typedef __attribute__((ext_vector_type(8))) short short8;   // 8 x bf16 (MFMA A/B frag)
typedef __attribute__((ext_vector_type(4))) float floatx4;  // MFMA C/D frag

// Problem constants: N=4000, E=60000, M=16, C=64, H=64, HEADS=8, A=8, VC=8, CE=32, Z=90
// cmp (fp32, per role stride RS): WeWa [32*64] @8192, WeWvWo [32*8] @11264
// packW (ushort, 18432): W frags [mat r0S,r0T,r1S,r1T][(t*2+kh)][lane][j 0..7]
//                        + P frags @16384: [Ps/Pt][kh][lane][j]
constexpr int RS = 11520;

__device__ inline float bf2f(ushort_t u) {
    union { unsigned int i; float f; } v; v.i = ((unsigned int)u) << 16; return v.f;
}
__device__ inline ushort_t f2bf(float f) {
    union { float f; unsigned int i; } v; v.f = f;
    unsigned int b = v.i + 0x7FFFu + ((v.i >> 16) & 1u);  // RNE
    return (ushort_t)(b >> 16);
}
__device__ inline void st4(ushort_t* dst, const floatx4& c) {
    uint2 v;
    v.x = (unsigned int)f2bf(c[0]) | ((unsigned int)f2bf(c[1]) << 16);
    v.y = (unsigned int)f2bf(c[2]) | ((unsigned int)f2bf(c[3]) << 16);
    *(uint2*)dst = v;
}

#define MFMA(a, b, c) __builtin_amdgcn_mfma_f32_16x16x32_bf16((a), (b), (c), 0, 0, 0)

// ---------------------------------------------------------------------------
// Kernel 1: weight composites (blocks 0..47) || zero binCnt (blocks 48..63)
// ---------------------------------------------------------------------------
__global__ __launch_bounds__(256) void k_prep(
    const float* __restrict__ Ws0, const float* __restrict__ Wt0, const float* __restrict__ We0,
    const float* __restrict__ Wa0, const float* __restrict__ Wv0, const float* __restrict__ Wo0,
    const float* __restrict__ Ws1, const float* __restrict__ Wt1, const float* __restrict__ We1,
    const float* __restrict__ Wa1, const float* __restrict__ Wv1, const float* __restrict__ Wo1,
    float* __restrict__ cmp, ushort_t* __restrict__ packW, int* __restrict__ binCnt, int N)
{
    int b = blockIdx.x;
    if (b >= 48) {
        int i = (b - 48) * 256 + threadIdx.x;
        if (i < N) binCnt[i] = 0;
        return;
    }
    int task = b % 6, r = (b / 6) % 2, z = b / 12;
    const float* Ws = r ? Ws1 : Ws0;
    const float* Wt = r ? Wt1 : Wt0;
    const float* We = r ? We1 : We0;
    const float* Wa = r ? Wa1 : Wa0;
    const float* Wv = r ? Wv1 : Wv0;
    const float* Wo = r ? Wo1 : Wo0;
    float* base = cmp + r * RS;

    if (task == 0 || task == 1) {
        // WsWa / WtWa -> fragment-packed bf16 only
        const float* L = task ? Wt : Ws;
        ushort_t* pw = packW + (r * 2 + task) * 4096;
        int lo = z * 1024;
        for (int idx = lo + threadIdx.x; idx < lo + 1024; idx += 256) {
            int c = idx >> 6, jc = idx & 63;
            float a = 0.f;
            #pragma unroll 8
            for (int k = 0; k < 64; ++k) a += L[c * 64 + k] * Wa[k * 64 + jc];
            int t = jc >> 4, n = jc & 15, kh = c >> 5, q = (c >> 3) & 3, jj = c & 7;
            pw[((t * 2 + kh) * 64 + q * 16 + n) * 8 + jj] = f2bf(a);
        }
    } else if (task == 2) {
        float* out = base + 8192;                       // WeWa linear fp32
        int lo = z * 512;
        for (int idx = lo + threadIdx.x; idx < lo + 512; idx += 256) {
            int ce = idx >> 6, jc = idx & 63;
            float a = 0.f;
            #pragma unroll 8
            for (int k = 0; k < 64; ++k) a += We[ce * 64 + k] * Wa[k * 64 + jc];
            out[idx] = a;
        }
    } else if (z == 0) {
        if (task == 5) {
            float* out = base + 11264;                  // WeWvWo linear fp32
            for (int idx = threadIdx.x; idx < 32 * 8; idx += 256) {
                int c = idx >> 3, h = idx & 7;
                float a = 0.f;
                for (int k = 0; k < 64; ++k) {
                    float wv = 0.f;
                    #pragma unroll
                    for (int aa = 0; aa < 8; ++aa) wv += Wv[k * 64 + h * 8 + aa] * Wo[h * 8 + aa];
                    a += We[c * 64 + k] * wv;
                }
                out[idx] = a;
            }
        } else {
            // task 3 (Ps) / 4 (Pt): write packed B-frags directly
            const float* L = (task == 3) ? Ws : Wt;
            ushort_t* pp = packW + 16384 + (task - 3) * 1024;
            for (int idx = threadIdx.x; idx < 64 * 8; idx += 256) {
                int c = idx >> 3, h = idx & 7;
                float a = 0.f;
                for (int k = 0; k < 64; ++k) {
                    float wv = 0.f;
                    #pragma unroll
                    for (int aa = 0; aa < 8; ++aa) wv += Wv[k * 64 + h * 8 + aa] * Wo[h * 8 + aa];
                    a += L[c * 64 + k] * wv;
                }
                int kh = c >> 5, q = (c >> 3) & 3, jj = c & 7;
                pp[kh * 512 + (q * 16 + r * 8 + h) * 8 + jj] = f2bf(a);
            }
        }
    }
}

// ---------------------------------------------------------------------------
// Kernel 2: per-node MFMA precompute (blocks < nodeBlocks) || dst histogram
// (blocks >= nodeBlocks). Weights staged in 36 KB LDS; one wave per node.
// srcA/tgtA stored TRANSPOSED [64 cols][16 rows] bf16 per (node,role).
// ---------------------------------------------------------------------------
__global__ __launch_bounds__(256, 4) void k_node_hist(
    const float* __restrict__ x, const int* __restrict__ mask,
    const ushort_t* __restrict__ packW,
    float* __restrict__ psrc, float* __restrict__ ptgt,
    ushort_t* __restrict__ srcA, ushort_t* __restrict__ tgtA,
    const int* __restrict__ ei, int* __restrict__ binCnt,
    int N, int nodeBlocks, int E)
{
    if (blockIdx.x >= nodeBlocks) {
        int e = (blockIdx.x - nodeBlocks) * 256 + threadIdx.x;
        if (e < E) atomicAdd(&binCnt[ei[E + e]], 1);
        return;
    }

    __shared__ __align__(16) ushort_t lw[18432];   // 36 KB
    for (int i = threadIdx.x; i < 2304; i += 256)
        ((short8*)lw)[i] = ((const short8*)packW)[i];
    __syncthreads();

    int wid  = (int)((blockIdx.x * blockDim.x + threadIdx.x) >> 6);
    int lane = threadIdx.x & 63;
    int q    = lane >> 4;     // quad 0..3
    int n16  = lane & 15;     // 0..15

    if (wid < N) {
        int nd = wid;
        // A fragments: x[nd] is [16,64] fp32, row m=n16, k base q*8
        const float* xp = x + (size_t)nd * 1024 + n16 * 64 + q * 8;
        float4 v0 = *(const float4*)(xp);
        float4 v1 = *(const float4*)(xp + 4);
        float4 v2 = *(const float4*)(xp + 32);
        float4 v3 = *(const float4*)(xp + 36);
        short8 a0, a1;
        a0[0] = (short)f2bf(v0.x); a0[1] = (short)f2bf(v0.y);
        a0[2] = (short)f2bf(v0.z); a0[3] = (short)f2bf(v0.w);
        a0[4] = (short)f2bf(v1.x); a0[5] = (short)f2bf(v1.y);
        a0[6] = (short)f2bf(v1.z); a0[7] = (short)f2bf(v1.w);
        a1[0] = (short)f2bf(v2.x); a1[1] = (short)f2bf(v2.y);
        a1[2] = (short)f2bf(v2.z); a1[3] = (short)f2bf(v2.w);
        a1[4] = (short)f2bf(v3.x); a1[5] = (short)f2bf(v3.y);
        a1[6] = (short)f2bf(v3.z); a1[7] = (short)f2bf(v3.w);

        int rsel = (mask[nd] != 0);
        const floatx4 zero = {0.f, 0.f, 0.f, 0.f};

        #define WF(mat, t, kh) (*(const short8*)&lw[(mat) * 4096 + ((t) * 2 + (kh)) * 512 + lane * 8])
        #define PF(m, kh)      (*(const short8*)&lw[16384 + (m) * 1024 + (kh) * 512 + lane * 8])

        {   // srcA role0 (mat 0)
            floatx4 c0 = zero, c1 = zero, c2 = zero, c3 = zero;
            c0 = MFMA(a0, WF(0,0,0), c0); c0 = MFMA(a1, WF(0,0,1), c0);
            c1 = MFMA(a0, WF(0,1,0), c1); c1 = MFMA(a1, WF(0,1,1), c1);
            c2 = MFMA(a0, WF(0,2,0), c2); c2 = MFMA(a1, WF(0,2,1), c2);
            c3 = MFMA(a0, WF(0,3,0), c3); c3 = MFMA(a1, WF(0,3,1), c3);
            ushort_t* sp = srcA + (size_t)nd * 2048 + n16 * 16 + q * 4;
            st4(sp, c0); st4(sp + 256, c1); st4(sp + 512, c2); st4(sp + 768, c3);
        }
        {   // srcA role1 (mat 2)
            floatx4 c0 = zero, c1 = zero, c2 = zero, c3 = zero;
            c0 = MFMA(a0, WF(2,0,0), c0); c0 = MFMA(a1, WF(2,0,1), c0);
            c1 = MFMA(a0, WF(2,1,0), c1); c1 = MFMA(a1, WF(2,1,1), c1);
            c2 = MFMA(a0, WF(2,2,0), c2); c2 = MFMA(a1, WF(2,2,1), c2);
            c3 = MFMA(a0, WF(2,3,0), c3); c3 = MFMA(a1, WF(2,3,1), c3);
            ushort_t* sp = srcA + (size_t)nd * 2048 + 1024 + n16 * 16 + q * 4;
            st4(sp, c0); st4(sp + 256, c1); st4(sp + 512, c2); st4(sp + 768, c3);
        }
        {   // tgtA selected role (mat 1 or 3) — wave-uniform branch
            int mt = rsel ? 3 : 1;
            floatx4 c0 = zero, c1 = zero, c2 = zero, c3 = zero;
            c0 = MFMA(a0, WF(mt,0,0), c0); c0 = MFMA(a1, WF(mt,0,1), c0);
            c1 = MFMA(a0, WF(mt,1,0), c1); c1 = MFMA(a1, WF(mt,1,1), c1);
            c2 = MFMA(a0, WF(mt,2,0), c2); c2 = MFMA(a1, WF(mt,2,1), c2);
            c3 = MFMA(a0, WF(mt,3,0), c3); c3 = MFMA(a1, WF(mt,3,1), c3);
            ushort_t* tp = tgtA + (size_t)nd * 1024 + n16 * 16 + q * 4;
            st4(tp, c0); st4(tp + 256, c1); st4(tp + 512, c2); st4(tp + 768, c3);
        }
        {   // Ps (both roles packed in cols) and Pt (selected role)
            floatx4 cp = zero;
            cp = MFMA(a0, PF(0,0), cp); cp = MFMA(a1, PF(0,1), cp);
            if (q == 0) {
                int r = n16 >> 3, h = n16 & 7;
                float* pp = psrc + (size_t)nd * 48 + r * 24 + h;
                pp[0]  = cp[1];
                pp[8]  = cp[2];
                pp[16] = cp[3];
            }
            floatx4 cq = zero;
            cq = MFMA(a0, PF(1,0), cq); cq = MFMA(a1, PF(1,1), cq);
            if (q == 0 && (n16 >> 3) == rsel) {
                int h = n16 & 7;
                float* pp = ptgt + (size_t)nd * 24 + h;
                pp[0]  = cq[1];
                pp[8]  = cq[2];
                pp[16] = cq[3];
            }
        }
        #undef WF
        #undef PF
    }
}

// ---------------------------------------------------------------------------
// Kernel 3: exclusive scan binCnt -> binStart (+ binPos cursor copy). 1 block.
// ---------------------------------------------------------------------------
__global__ __launch_bounds__(256) void k_scan(
    const int* __restrict__ binCnt, int* __restrict__ binStart,
    int* __restrict__ binPos, int N)
{
    __shared__ int part[256];
    int t = threadIdx.x;
    int chunk = (N + 255) / 256;
    int lo = t * chunk, hi = lo + chunk;
    if (lo > N) lo = N;
    if (hi > N) hi = N;
    int s = 0;
    for (int i = lo; i < hi; ++i) s += binCnt[i];
    part[t] = s;
    __syncthreads();
    for (int off = 1; off < 256; off <<= 1) {
        int v = (t >= off) ? part[t - off] : 0;
        __syncthreads();
        part[t] += v;
        __syncthreads();
    }
    int start = (t == 0) ? 0 : part[t - 1];
    for (int i = lo; i < hi; ++i) {
        int c = binCnt[i];
        binStart[i] = start; binPos[i] = start;
        start += c;
    }
}

// ---------------------------------------------------------------------------
// Kernel 4: scatter edges into dst-sorted order[] (counting sort)
// ---------------------------------------------------------------------------
__global__ __launch_bounds__(256) void k_scatter(
    const int* __restrict__ ei, int* __restrict__ binPos,
    int* __restrict__ order, int E)
{
    int e = blockIdx.x * 256 + threadIdx.x;
    if (e < E) {
        int pos = atomicAdd(&binPos[ei[E + e]], 1);
        order[pos] = e;
    }
}

// ---------------------------------------------------------------------------
// Kernel 5: segment reduce — ONE WAVE PER DST NODE. Loops the node's
// incoming edges (dst-sorted via order[]), accumulating den/num in REGISTERS:
// zero atomics (R5's sorted+atomics line ping-pong: WRITE 7.5->367 MB),
// tgtA/ptgt/embt/va loaded once per node, and the final division + head-sum
// (old k_out) folds into the epilogue. Writes out[] directly.
// ---------------------------------------------------------------------------
__global__ __launch_bounds__(256, 4) void k_seg(
    const int* __restrict__ ei, const float* __restrict__ dist,
    const int* __restrict__ zn, const int* __restrict__ mask,
    const float* __restrict__ wig, const float* __restrict__ cmp,
    const float* __restrict__ embs0, const float* __restrict__ embt0, const float* __restrict__ wd0,
    const float* __restrict__ embs1, const float* __restrict__ embt1, const float* __restrict__ wd1,
    const float* __restrict__ va0, const float* __restrict__ va1,
    const ushort_t* __restrict__ srcA, const ushort_t* __restrict__ tgtA,
    const float* __restrict__ psrc, const float* __restrict__ ptgt,
    const int* __restrict__ order, const int* __restrict__ binStart,
    const int* __restrict__ binCnt,
    float* __restrict__ out, int N, int E)
{
    int wv = threadIdx.x >> 6, j = threadIdx.x & 63;
    int dst = blockIdx.x * 4 + wv;
    if (dst >= N) return;
    int hq = j >> 3, h8 = j & 7, ce = j & 31;
    int r = (mask[dst] != 0);
    int zt = zn[dst];

    // per-dst invariants (loaded once)
    const ushort_t* ta = tgtA + (size_t)dst * 1024 + j * 16;
    short8 tv0 = *(const short8*)(ta);       // rows 0..7 of col j
    short8 tv1 = *(const short8*)(ta + 8);   // rows 8..15
    float pvt = (h8 < 3) ? ptgt[(size_t)dst * 24 + h8 * 8 + hq] : 0.f;
    float emt = (r ? embt1 : embt0)[zt * 32 + ce];
    float wdc = (r ? wd1 : wd0)[ce];
    float vaj = (r ? va1 : va0)[j];
    const float* embs   = r ? embs1 : embs0;
    const float* WeWa   = cmp + r * RS + 8192;
    const float* WeWvWo = cmp + r * RS + 11264;

    int s0 = binStart[dst], cnt = binCnt[dst];
    float accd = 0.f, accn = 0.f;

    for (int t = 0; t < cnt; ++t) {
        int e = order[s0 + t];
        int src = ei[e];
        float d = dist[e];
        int zs = zn[src];

        const float* w0 = wig + (size_t)e * 256;        // D[0, :]
        float4 wA = *(const float4*)(w0);
        float4 wB = *(const float4*)(w0 + 4);
        float4 wC = *(const float4*)(w0 + 8);
        float4 wD = *(const float4*)(w0 + 12);
        const ushort_t* sa = srcA + (size_t)src * 2048 + r * 1024 + j * 16;
        short8 sv0 = *(const short8*)(sa);
        short8 sv1 = *(const short8*)(sa + 8);
        float pv = pvt;
        if (h8 < 3) pv += psrc[(size_t)src * 48 + r * 24 + h8 * 8 + hq];

        // edge scalar embedding (32 values via j&31)
        float z = d * wdc + embs[zs * 32 + ce] + emt;
        float es = z / (1.f + __expf(-z));              // silu

        float f0a = 0.f, ej = 0.f;
        #pragma unroll
        for (int cc = 0; cc < 32; ++cc) {
            float ev = __shfl(es, cc, 64);
            f0a += ev * WeWa[cc * 64 + j];
            ej  += ev * WeWvWo[cc * 8 + hq];
        }

        // f0a[j] += sum_n D[0,n] * (ysa[src][n,j] + yta[dst][n,j])
        f0a += wA.x * (bf2f((ushort_t)sv0[0]) + bf2f((ushort_t)tv0[0]));
        f0a += wA.y * (bf2f((ushort_t)sv0[1]) + bf2f((ushort_t)tv0[1]));
        f0a += wA.z * (bf2f((ushort_t)sv0[2]) + bf2f((ushort_t)tv0[2]));
        f0a += wA.w * (bf2f((ushort_t)sv0[3]) + bf2f((ushort_t)tv0[3]));
        f0a += wB.x * (bf2f((ushort_t)sv0[4]) + bf2f((ushort_t)tv0[4]));
        f0a += wB.y * (bf2f((ushort_t)sv0[5]) + bf2f((ushort_t)tv0[5]));
        f0a += wB.z * (bf2f((ushort_t)sv0[6]) + bf2f((ushort_t)tv0[6]));
        f0a += wB.w * (bf2f((ushort_t)sv0[7]) + bf2f((ushort_t)tv0[7]));
        f0a += wC.x * (bf2f((ushort_t)sv1[0]) + bf2f((ushort_t)tv1[0]));
        f0a += wC.y * (bf2f((ushort_t)sv1[1]) + bf2f((ushort_t)tv1[1]));
        f0a += wC.z * (bf2f((ushort_t)sv1[2]) + bf2f((ushort_t)tv1[2]));
        f0a += wC.w * (bf2f((ushort_t)sv1[3]) + bf2f((ushort_t)tv1[3]));
        f0a += wD.x * (bf2f((ushort_t)sv1[4]) + bf2f((ushort_t)tv1[4]));
        f0a += wD.y * (bf2f((ushort_t)sv1[5]) + bf2f((ushort_t)tv1[5]));
        f0a += wD.z * (bf2f((ushort_t)sv1[6]) + bf2f((ushort_t)tv1[6]));
        f0a += wD.w * (bf2f((ushort_t)sv1[7]) + bf2f((ushort_t)tv1[7]));

        float la = f0a > 0.f ? f0a : 0.2f * f0a;        // leaky_relu(0.2)
        float val = la * vaj;
        val += __shfl_xor(val, 1);
        val += __shfl_xor(val, 2);
        val += __shfl_xor(val, 4);                      // logit per 8-lane group
        float ex = __expf(val);                         // no-max softmax (logits bounded)

        accd += ex;
        if (h8 < 3) {
            float w0k = (h8 == 0) ? wA.y : (h8 == 1) ? wA.z : wA.w;  // D[0,1..3]
            accn += ex * (pv + ej * w0k);
        }
    }

    // out[dst,k] = sum_h num[h,k] / (den[h]+eps); num(k=h8,h=hq) lives in
    // lane hq*8+h8 (h8<3). xor 8/16/32 sums over hq within each h8 family.
    float contrib = (h8 < 3) ? accn / (accd + 1e-9f) : 0.f;
    contrib += __shfl_xor(contrib, 8);
    contrib += __shfl_xor(contrib, 16);
    contrib += __shfl_xor(contrib, 32);
    if (j < 3) out[dst * 3 + j] = contrib;
}

// ---------------------------------------------------------------------------
extern "C" void kernel_launch(void* const* d_in, const int* in_sizes, int n_in,
                              void* d_out, int out_size, void* d_ws, size_t ws_size,
                              hipStream_t stream) {
    const float* x    = (const float*)d_in[0];
    const int*   zn   = (const int*)d_in[1];
    const float* dist = (const float*)d_in[2];
    const int*   ei   = (const int*)d_in[3];
    const int*   mask = (const int*)d_in[4];
    const float* wig  = (const float*)d_in[5];
    // per role: emb_s, emb_t, w_d, We, Ws, Wt, Wa, va, Wv, Wo
    const float* fs[10]; const float* dn[10];
    for (int i = 0; i < 10; ++i) { fs[i] = (const float*)d_in[6 + i]; dn[i] = (const float*)d_in[16 + i]; }

    int N = in_sizes[1];   // atomic_numbers count
    int E = in_sizes[2];   // edge_distance count

    // workspace carve-up
    float* cmp  = (float*)d_ws;                    // 2*RS = 23040 floats
    float* psrc = cmp + 2 * RS;                    // N*48
    float* ptgt = psrc + (size_t)N * 48;           // N*24
    ushort_t* srcA = (ushort_t*)(ptgt + (size_t)N * 24);  // N*2048 bf16
    ushort_t* tgtA = srcA + (size_t)N * 2048;             // N*1024 bf16
    ushort_t* packW = tgtA + (size_t)N * 1024;            // 18432 ushorts (36 KB)
    int* binCnt   = (int*)(packW + 18432);                // N
    int* binPos   = binCnt + N;                           // N
    int* binStart = binPos + N;                           // N
    int* order    = binStart + N;                         // E
    // total ~26 MB

    int zeroBlocks = (N + 255) / 256;
    k_prep<<<48 + zeroBlocks, 256, 0, stream>>>(
        fs[4], fs[5], fs[3], fs[6], fs[8], fs[9],
        dn[4], dn[5], dn[3], dn[6], dn[8], dn[9], cmp, packW, binCnt, N);

    int nodeBlocks = (N + 3) / 4;
    int histBlocks = (E + 255) / 256;
    k_node_hist<<<nodeBlocks + histBlocks, 256, 0, stream>>>(
        x, mask, packW, psrc, ptgt, srcA, tgtA, ei, binCnt, N, nodeBlocks, E);

    k_scan<<<1, 256, 0, stream>>>(binCnt, binStart, binPos, N);

    k_scatter<<<histBlocks, 256, 0, stream>>>(ei, binPos, order, E);

    k_seg<<<(N + 3) / 4, 256, 0, stream>>>(
        ei, dist, zn, mask, wig, cmp,
        fs[0], fs[1], fs[2], dn[0], dn[1], dn[2],
        fs[7], dn[7], srcA, tgtA, psrc, ptgt,
        order, binStart, binCnt, (float*)d_out, N, E);
}